// Round 3
// baseline (1319.593 us; speedup 1.0000x reference)
//
#include <hip/hip_runtime.h>

// Problem constants
#define NN 128
#define CC 64          // C_IN == C_OUT
#define TT 256
#define VV 25
#define NSUB 3
#define TCH 8                  // t-rows per block tile
#define LPOS (TCH*VV)          // 200 positions per block tile
#define NCHUNK (TT/TCH)        // 32 chunks per n
#define CNT (NN*TT*VV)         // 819200 positions per channel

// workspace layout (float offsets)
#define WS_BEFF 80      // 64:  b_eff
#define WS_GSUM 144     // 64:  global sum of y (hidden minus bias)
#define WS_GSQ  208     // 64:  global sum of y^2
#define WS_W    320     // 25*64*64: W_eff then (in-place) M_fin, [v][c][o]; 256B-aligned rows
#define WS_BFIN (WS_W + VV*CC*CC)   // 64: folded bias

// 8 FMAs of one x scalar against a W float4-pair
#define FMA8(xx, q0, q1) \
    acc[0]=fmaf(xx,(q0).x,acc[0]); acc[1]=fmaf(xx,(q0).y,acc[1]); \
    acc[2]=fmaf(xx,(q0).z,acc[2]); acc[3]=fmaf(xx,(q0).w,acc[3]); \
    acc[4]=fmaf(xx,(q1).x,acc[4]); acc[5]=fmaf(xx,(q1).y,acc[5]); \
    acc[6]=fmaf(xx,(q1).z,acc[6]); acc[7]=fmaf(xx,(q1).w,acc[7]);

// load 4 consecutive c-rows (2 float4 each) of W into 8 named float4 regs.
// All offsets are compile-time constants off a loop-invariant base -> the
// compiler folds them into global_load offset immediates (no per-load VALU).
#define LOADW(d0,d1,d2,d3,d4,d5,d6,d7, base) \
    d0 = *(const float4*)((base));            d1 = *(const float4*)((base) + 4); \
    d2 = *(const float4*)((base) + CC);       d3 = *(const float4*)((base) + CC + 4); \
    d4 = *(const float4*)((base) + 2*CC);     d5 = *(const float4*)((base) + 2*CC + 4); \
    d6 = *(const float4*)((base) + 3*CC);     d7 = *(const float4*)((base) + 3*CC + 4);

// fused: rowsums (in LDS), W_eff build, b_eff, and gsum/gsq zeroing
__global__ void k_weff(const float* __restrict__ A, const float* __restrict__ ga,
                       const float* __restrict__ gw, const float* __restrict__ gb,
                       float* __restrict__ ws) {
    __shared__ float S[NSUB*VV];
    int tid = threadIdx.x;
    if (tid < NSUB*VV) {
        int i = tid / VV, v = tid % VV;
        const float* pa = A  + (i*VV + v)*VV;
        const float* pg = ga + (i*VV + v)*VV;
        float s = 0.f;
        for (int w2 = 0; w2 < VV; ++w2) s += pa[w2] + pg[w2];
        S[tid] = s;
    }
    __syncthreads();
    int idx = blockIdx.x*256 + tid;
    int v = idx >> 12;
    int c = (idx >> 6) & 63;
    int o = idx & 63;
    float acc = 0.f;
    #pragma unroll
    for (int i = 0; i < NSUB; ++i)
        acc = fmaf(gw[(i*CC + o)*CC + c], 1.f + S[i*VV + v], acc);
    ws[WS_W + idx] = acc;
    if (blockIdx.x == 0 && tid < CC)
        ws[WS_BEFF + tid] = gb[tid] + gb[CC + tid] + gb[2*CC + tid];
    if (blockIdx.x == 1 && tid < 128)
        ws[WS_GSUM + tid] = 0.f;   // zeros gsum(64)+gsq(64), contiguous
}

// Heavy pass structure (k_stats / k_final):
//   block = (n, 8-t chunk); Xs[c][tl*25+v] staged coalesced (proven r0 code).
//   wave w serially owns v = w+4k (wave-uniform -> W loads hit ONE 256B row).
//   lane: og=lane>>3 (8 o's in acc[8]), tl=lane&7 (t).
//   NEW (r3): explicit register ping-pong on W (two 4-c buffers of 8 float4).
//   Each half issues 8 loads for the other buffer before its 32 FMAs, and the
//   cg==56 prefetch targets the NEXT v's c=0..3 -> the pipeline never drains
//   (counted vmcnt, ~8-16 loads in flight per wave; need ~31/SIMD at 3 waves).
__global__ __launch_bounds__(256, 3) void k_stats(const float* __restrict__ x,
                                                  const float* __restrict__ wsw,
                                                  float* __restrict__ gsum,
                                                  float* __restrict__ gsq) {
    __shared__ __align__(16) float Xs[CC*LPOS];
    __shared__ float s_sum[CC], s_sq[CC];
    int tid = threadIdx.x;
    int w = tid >> 6, lane = tid & 63;
    int og = lane >> 3, tl = lane & 7;
    int n = blockIdx.x >> 5, ch = blockIdx.x & 31;
    const float* xb = x + (size_t)n*(CC*TT*VV) + ch*LPOS;
    if (tid < CC) { s_sum[tid] = 0.f; s_sq[tid] = 0.f; }
    for (int i4 = tid; i4 < CC*(LPOS/4); i4 += 256) {
        int c = i4 / (LPOS/4), j4 = i4 - c*(LPOS/4);
        *(float4*)&Xs[c*LPOS + j4*4] = *(const float4*)(xb + c*(TT*VV) + j4*4);
    }
    __syncthreads();
    float rs[8], rsq[8];
    #pragma unroll
    for (int oi = 0; oi < 8; ++oi) { rs[oi] = 0.f; rsq[oi] = 0.f; }
    int kmax = (w == 0) ? 7 : 6;
    const float* wp = wsw + w*(CC*CC) + og*8;
    const float* xp = Xs + tl*VV + w;
    float4 a0,a1,a2,a3,a4,a5,a6,a7, b0,b1,b2,b3,b4,b5,b6,b7;
    LOADW(a0,a1,a2,a3,a4,a5,a6,a7, wp)                      // v=w, c=0..3
    for (int k = 0; k < kmax; ++k) {
        float acc[8] = {0.f,0.f,0.f,0.f,0.f,0.f,0.f,0.f};
        const float* wnext = (k == kmax-1) ? wp : (wp + 4*CC*CC); // clamp: no OOB
        #pragma unroll
        for (int cg = 0; cg < CC; cg += 8) {
            LOADW(b0,b1,b2,b3,b4,b5,b6,b7, wp + (cg+4)*CC)  // c=cg+4..cg+7
            float x0 = xp[(cg+0)*LPOS], x1 = xp[(cg+1)*LPOS],
                  x2 = xp[(cg+2)*LPOS], x3 = xp[(cg+3)*LPOS];
            FMA8(x0, a0, a1) FMA8(x1, a2, a3) FMA8(x2, a4, a5) FMA8(x3, a6, a7)
            const float* nb = (cg == CC-8) ? wnext : (wp + (cg+8)*CC);
            LOADW(a0,a1,a2,a3,a4,a5,a6,a7, nb)              // next 4 c (or next v c=0..3)
            float x4 = xp[(cg+4)*LPOS], x5 = xp[(cg+5)*LPOS],
                  x6 = xp[(cg+6)*LPOS], x7 = xp[(cg+7)*LPOS];
            FMA8(x4, b0, b1) FMA8(x5, b2, b3) FMA8(x6, b4, b5) FMA8(x7, b6, b7)
        }
        #pragma unroll
        for (int oi = 0; oi < 8; ++oi) {
            rs[oi] += acc[oi];
            rsq[oi] = fmaf(acc[oi], acc[oi], rsq[oi]);
        }
        wp += 4*CC*CC;
        xp += 4;
    }
    // reduce over tl (lane bits 0..2); og bits untouched
    #pragma unroll
    for (int m = 1; m <= 4; m <<= 1) {
        #pragma unroll
        for (int oi = 0; oi < 8; ++oi) {
            rs[oi]  += __shfl_xor(rs[oi],  m);
            rsq[oi] += __shfl_xor(rsq[oi], m);
        }
    }
    if (tl == 0) {
        #pragma unroll
        for (int oi = 0; oi < 8; ++oi) {
            atomicAdd(&s_sum[og*8 + oi], rs[oi]);
            atomicAdd(&s_sq[og*8 + oi],  rsq[oi]);
        }
    }
    __syncthreads();
    if (tid < CC) {
        atomicAdd(&gsum[tid], s_sum[tid]);
        atomicAdd(&gsq[tid],  s_sq[tid]);
    }
}

// fold BN into the matrix in-place: M = alpha*W_eff + I; b_fin = beta + alpha*(b_eff - mean)
__global__ void k_mid(float* __restrict__ ws, const float* __restrict__ gamma,
                      const float* __restrict__ beta) {
    int idx = blockIdx.x*256 + threadIdx.x;
    int c = (idx >> 6) & 63;
    int o = idx & 63;
    float b     = ws[WS_BEFF + o];
    float meanY = ws[WS_GSUM + o] * (1.f/CNT);
    float ey2   = ws[WS_GSQ  + o] * (1.f/CNT);
    float m   = meanY + b;                          // E[hidden]
    float var = ey2 + 2.f*b*meanY + b*b - m*m;      // biased variance
    float alpha = gamma[o] * rsqrtf(var + 1e-5f);
    float wv = ws[WS_W + idx];
    ws[WS_W + idx] = fmaf(alpha, wv, (c == o) ? 1.f : 0.f);  // fold identity residual
    if (blockIdx.x == 0 && threadIdx.x < CC)
        ws[WS_BFIN + o] = fmaf(alpha, b - m, beta[o]);
}

__global__ __launch_bounds__(256, 3) void k_final(const float* __restrict__ x,
                                                  const float* __restrict__ ws,
                                                  float* __restrict__ out) {
    __shared__ __align__(16) float Xs[CC*LPOS];
    int tid = threadIdx.x;
    int w = tid >> 6, lane = tid & 63;
    int og = lane >> 3, tl = lane & 7;
    int n = blockIdx.x >> 5, ch = blockIdx.x & 31;
    const float* xb = x + (size_t)n*(CC*TT*VV) + ch*LPOS;
    float bf[8];
    #pragma unroll
    for (int oi = 0; oi < 8; ++oi) bf[oi] = ws[WS_BFIN + og*8 + oi];
    for (int i4 = tid; i4 < CC*(LPOS/4); i4 += 256) {
        int c = i4 / (LPOS/4), j4 = i4 - c*(LPOS/4);
        *(float4*)&Xs[c*LPOS + j4*4] = *(const float4*)(xb + c*(TT*VV) + j4*4);
    }
    __syncthreads();
    int kmax = (w == 0) ? 7 : 6;
    const float* wp = ws + WS_W + w*(CC*CC) + og*8;
    const float* xp = Xs + tl*VV + w;
    float4 a0,a1,a2,a3,a4,a5,a6,a7, b0,b1,b2,b3,b4,b5,b6,b7;
    LOADW(a0,a1,a2,a3,a4,a5,a6,a7, wp)
    for (int k = 0; k < kmax; ++k) {
        float acc[8] = {0.f,0.f,0.f,0.f,0.f,0.f,0.f,0.f};
        const float* wnext = (k == kmax-1) ? wp : (wp + 4*CC*CC);
        #pragma unroll
        for (int cg = 0; cg < CC; cg += 8) {
            LOADW(b0,b1,b2,b3,b4,b5,b6,b7, wp + (cg+4)*CC)
            float x0 = xp[(cg+0)*LPOS], x1 = xp[(cg+1)*LPOS],
                  x2 = xp[(cg+2)*LPOS], x3 = xp[(cg+3)*LPOS];
            FMA8(x0, a0, a1) FMA8(x1, a2, a3) FMA8(x2, a4, a5) FMA8(x3, a6, a7)
            const float* nb = (cg == CC-8) ? wnext : (wp + (cg+8)*CC);
            LOADW(a0,a1,a2,a3,a4,a5,a6,a7, nb)
            float x4 = xp[(cg+4)*LPOS], x5 = xp[(cg+5)*LPOS],
                  x6 = xp[(cg+6)*LPOS], x7 = xp[(cg+7)*LPOS];
            FMA8(x4, b0, b1) FMA8(x5, b2, b3) FMA8(x6, b4, b5) FMA8(x7, b6, b7)
        }
        // write y back in-place into the (now dead) x-column v of Xs.
        // Column v is owned exclusively by this wave -> no race, no barrier.
        float* yp = (float*)xp;
        #pragma unroll
        for (int oi = 0; oi < 8; ++oi)
            yp[(og*8 + oi)*LPOS] = fmaxf(acc[oi] + bf[oi], 0.f);
        wp += 4*CC*CC;
        xp += 4;
    }
    __syncthreads();
    // coalesced float4 readout: Xs rows now hold y[o][tl*25+v]
    float* ob = out + (size_t)n*(CC*TT*VV) + ch*LPOS;
    for (int i4 = tid; i4 < CC*(LPOS/4); i4 += 256) {
        int o = i4 / (LPOS/4), j4 = i4 - o*(LPOS/4);
        *(float4*)(ob + o*(TT*VV) + j4*4) = *(const float4*)&Xs[o*LPOS + j4*4];
    }
}

extern "C" void kernel_launch(void* const* d_in, const int* in_sizes, int n_in,
                              void* d_out, int out_size, void* d_ws, size_t ws_size,
                              hipStream_t stream) {
    const float* x     = (const float*)d_in[0];
    const float* A     = (const float*)d_in[1];
    const float* ga    = (const float*)d_in[2];
    // d_in[3..6] = a_w, a_b, b_w, b_b: provably unused (softmax over contracted axis sums to 1)
    const float* gw    = (const float*)d_in[7];
    const float* gb    = (const float*)d_in[8];
    const float* gamma = (const float*)d_in[9];
    const float* beta  = (const float*)d_in[10];
    float* ws  = (float*)d_ws;
    float* out = (float*)d_out;

    hipLaunchKernelGGL(k_weff,  dim3(400), dim3(256), 0, stream, A, ga, gw, gb, ws);
    hipLaunchKernelGGL(k_stats, dim3(NN*NCHUNK), dim3(256), 0, stream,
                       x, ws + WS_W, ws + WS_GSUM, ws + WS_GSQ);
    hipLaunchKernelGGL(k_mid,   dim3(400), dim3(256), 0, stream, ws, gamma, beta);
    hipLaunchKernelGGL(k_final, dim3(NN*NCHUNK), dim3(256), 0, stream, x, ws, out);
}

// Round 4
// 800.258 us; speedup vs baseline: 1.6490x; 1.6490x over previous
//
#include <hip/hip_runtime.h>

// Problem constants
#define NN 128
#define CC 64          // C_IN == C_OUT
#define TT 256
#define VV 25
#define NSUB 3
#define TCH 8                  // t-rows per block tile
#define LPOS (TCH*VV)          // 200 positions per block tile
#define NCHUNK (TT/TCH)        // 32 chunks per n
#define CNT (NN*TT*VV)         // 819200 positions per channel
#define XSTR 204               // padded LDS row stride: %4==0 (float4 ok), breaks 8-way og bank collisions
#define WROW (VV*CC)           // 1600: c-row stride of transposed W [c][v][o]

// workspace layout (float offsets)
#define WS_BEFF 80      // 64:  b_eff
#define WS_GSUM 144     // 64:  global sum of y (hidden minus bias)
#define WS_GSQ  208     // 64:  global sum of y^2
#define WS_W    320     // 25*64*64: W stored TRANSPOSED [c][v][o]; then in-place M_fin
#define WS_BFIN (WS_W + VV*CC*CC)   // 64: folded bias

// fused: rowsums (in LDS), W_eff build (transposed), b_eff, and gsum/gsq zeroing
__global__ void k_weff(const float* __restrict__ A, const float* __restrict__ ga,
                       const float* __restrict__ gw, const float* __restrict__ gb,
                       float* __restrict__ ws) {
    __shared__ float S[NSUB*VV];
    int tid = threadIdx.x;
    if (tid < NSUB*VV) {
        int i = tid / VV, v = tid % VV;
        const float* pa = A  + (i*VV + v)*VV;
        const float* pg = ga + (i*VV + v)*VV;
        float s = 0.f;
        for (int w2 = 0; w2 < VV; ++w2) s += pa[w2] + pg[w2];
        S[tid] = s;
    }
    __syncthreads();
    int idx = blockIdx.x*256 + tid;
    int v = idx >> 12;
    int c = (idx >> 6) & 63;
    int o = idx & 63;
    float acc = 0.f;
    #pragma unroll
    for (int i = 0; i < NSUB; ++i)
        acc = fmaf(gw[(i*CC + o)*CC + c], 1.f + S[i*VV + v], acc);
    ws[WS_W + c*WROW + v*CC + o] = acc;          // transposed store [c][v][o]
    if (blockIdx.x == 0 && tid < CC)
        ws[WS_BEFF + tid] = gb[tid] + gb[CC + tid] + gb[2*CC + tid];
    if (blockIdx.x == 1 && tid < 128)
        ws[WS_GSUM + tid] = 0.f;   // zeros gsum(64)+gsq(64), contiguous
}

// Heavy pass structure (k_stats / k_final) — r0 compute density + coalesced W:
//   block = (n, 8-t chunk); Xs[c][t*25+v] staged coalesced, row stride 204.
//   thread (tid<200): og = tid&7 (o-octet), v = tid>>3. Holds xv[8] (t) and
//   acc[8][8] -> 2 W float4 loads per c serve 64 FMAs (32 FMA/load).
//   W is [c][v][o]: a wave (8 v x 8 og) reads a CONTIGUOUS 1024B chunk of one
//   256B-aligned c-row per load instr (16 lines, minimal) -- no gather.
//   In-flight need: 1 load / 64 FMA-cyc / wave -> ~12 per SIMD; unroll 4 covers.
__global__ __launch_bounds__(256, 2) void k_stats(const float* __restrict__ x,
                                                  const float* __restrict__ wsw,
                                                  float* __restrict__ gsum,
                                                  float* __restrict__ gsq) {
    __shared__ __align__(16) float Xs[CC*XSTR];
    __shared__ float s_sum[CC], s_sq[CC];
    int tid = threadIdx.x;
    int n = blockIdx.x >> 5, ch = blockIdx.x & 31;
    const float* xb = x + (size_t)n*(CC*TT*VV) + ch*LPOS;
    if (tid < CC) { s_sum[tid] = 0.f; s_sq[tid] = 0.f; }
    for (int i4 = tid; i4 < CC*(LPOS/4); i4 += 256) {
        int c = i4 / (LPOS/4), j4 = i4 - c*(LPOS/4);
        *(float4*)&Xs[c*XSTR + j4*4] = *(const float4*)(xb + c*(TT*VV) + j4*4);
    }
    __syncthreads();
    if (tid < 200) {
        int og = tid & 7, v = tid >> 3, o0 = og*8;
        float acc[TCH][8];
        #pragma unroll
        for (int t = 0; t < TCH; ++t)
            #pragma unroll
            for (int b = 0; b < 8; ++b) acc[t][b] = 0.f;
        const float* wp = wsw + v*CC + o0;       // [c][v][o], c-stride WROW
        const float* xp = Xs + v;
        #pragma unroll 4
        for (int c = 0; c < CC; ++c) {
            const float* wr = wp + c*WROW;
            float4 w0 = *(const float4*)(wr);
            float4 w1 = *(const float4*)(wr + 4);
            float xv[TCH];
            #pragma unroll
            for (int t = 0; t < TCH; ++t) xv[t] = xp[c*XSTR + t*VV];
            #pragma unroll
            for (int t = 0; t < TCH; ++t) {
                float xx = xv[t];
                acc[t][0] = fmaf(xx, w0.x, acc[t][0]);
                acc[t][1] = fmaf(xx, w0.y, acc[t][1]);
                acc[t][2] = fmaf(xx, w0.z, acc[t][2]);
                acc[t][3] = fmaf(xx, w0.w, acc[t][3]);
                acc[t][4] = fmaf(xx, w1.x, acc[t][4]);
                acc[t][5] = fmaf(xx, w1.y, acc[t][5]);
                acc[t][6] = fmaf(xx, w1.z, acc[t][6]);
                acc[t][7] = fmaf(xx, w1.w, acc[t][7]);
            }
        }
        #pragma unroll
        for (int oi = 0; oi < 8; ++oi) {
            float s1 = 0.f, s2 = 0.f;
            #pragma unroll
            for (int t = 0; t < TCH; ++t) {
                s1 += acc[t][oi];
                s2 = fmaf(acc[t][oi], acc[t][oi], s2);
            }
            atomicAdd(&s_sum[o0+oi], s1);
            atomicAdd(&s_sq[o0+oi],  s2);
        }
    }
    __syncthreads();
    if (tid < CC) {
        atomicAdd(&gsum[tid], s_sum[tid]);
        atomicAdd(&gsq[tid],  s_sq[tid]);
    }
}

// fold BN into the matrix in-place: M = alpha*W + I; b_fin = beta + alpha*(b_eff - mean)
// idx decodes the TRANSPOSED layout [c][v][o]: o = idx&63 (WROW%64==0), c = idx/WROW
__global__ void k_mid(float* __restrict__ ws, const float* __restrict__ gamma,
                      const float* __restrict__ beta) {
    int idx = blockIdx.x*256 + threadIdx.x;
    int o = idx & 63;
    int c = idx / WROW;
    float b     = ws[WS_BEFF + o];
    float meanY = ws[WS_GSUM + o] * (1.f/CNT);
    float ey2   = ws[WS_GSQ  + o] * (1.f/CNT);
    float m   = meanY + b;                          // E[hidden]
    float var = ey2 + 2.f*b*meanY + b*b - m*m;      // biased variance
    float alpha = gamma[o] * rsqrtf(var + 1e-5f);
    float wv = ws[WS_W + idx];
    ws[WS_W + idx] = fmaf(alpha, wv, (c == o) ? 1.f : 0.f);  // fold identity residual
    if (blockIdx.x == 0 && threadIdx.x < CC)
        ws[WS_BFIN + o] = fmaf(alpha, b - m, beta[o]);
}

__global__ __launch_bounds__(256, 2) void k_final(const float* __restrict__ x,
                                                  const float* __restrict__ ws,
                                                  float* __restrict__ out) {
    __shared__ __align__(16) float Xs[CC*XSTR];
    int tid = threadIdx.x;
    int n = blockIdx.x >> 5, ch = blockIdx.x & 31;
    const float* xb = x + (size_t)n*(CC*TT*VV) + ch*LPOS;
    for (int i4 = tid; i4 < CC*(LPOS/4); i4 += 256) {
        int c = i4 / (LPOS/4), j4 = i4 - c*(LPOS/4);
        *(float4*)&Xs[c*XSTR + j4*4] = *(const float4*)(xb + c*(TT*VV) + j4*4);
    }
    __syncthreads();
    if (tid < 200) {
        int og = tid & 7, v = tid >> 3, o0 = og*8;
        float acc[TCH][8];
        #pragma unroll
        for (int t = 0; t < TCH; ++t)
            #pragma unroll
            for (int b = 0; b < 8; ++b) acc[t][b] = 0.f;
        const float* wp = ws + WS_W + v*CC + o0;
        const float* xp = Xs + v;
        #pragma unroll 4
        for (int c = 0; c < CC; ++c) {
            const float* wr = wp + c*WROW;
            float4 w0 = *(const float4*)(wr);
            float4 w1 = *(const float4*)(wr + 4);
            float xv[TCH];
            #pragma unroll
            for (int t = 0; t < TCH; ++t) xv[t] = xp[c*XSTR + t*VV];
            #pragma unroll
            for (int t = 0; t < TCH; ++t) {
                float xx = xv[t];
                acc[t][0] = fmaf(xx, w0.x, acc[t][0]);
                acc[t][1] = fmaf(xx, w0.y, acc[t][1]);
                acc[t][2] = fmaf(xx, w0.z, acc[t][2]);
                acc[t][3] = fmaf(xx, w0.w, acc[t][3]);
                acc[t][4] = fmaf(xx, w1.x, acc[t][4]);
                acc[t][5] = fmaf(xx, w1.y, acc[t][5]);
                acc[t][6] = fmaf(xx, w1.z, acc[t][6]);
                acc[t][7] = fmaf(xx, w1.w, acc[t][7]);
            }
        }
        // y writeback into the (dead) column-v address set of Xs.
        // Column v touched only by the 8 og-threads of v = same wave (tids 8v..8v+7),
        // which have all finished reading it (in-order wave) -> race-free.
        // oi rotated by og so the 8 og-lanes land in distinct banks (XSTR=204).
        #pragma unroll
        for (int r = 0; r < 8; ++r) {
            int oi = (r + og) & 7;
            float bfo = ws[WS_BFIN + o0 + oi];
            #pragma unroll
            for (int t = 0; t < TCH; ++t)
                Xs[(o0+oi)*XSTR + t*VV + v] = fmaxf(acc[t][oi] + bfo, 0.f);
        }
    }
    __syncthreads();
    // coalesced float4 readout: Xs rows hold y[o][t*25+v]
    float* ob = out + (size_t)n*(CC*TT*VV) + ch*LPOS;
    for (int i4 = tid; i4 < CC*(LPOS/4); i4 += 256) {
        int o = i4 / (LPOS/4), j4 = i4 - o*(LPOS/4);
        *(float4*)(ob + o*(TT*VV) + j4*4) = *(const float4*)&Xs[o*XSTR + j4*4];
    }
}

extern "C" void kernel_launch(void* const* d_in, const int* in_sizes, int n_in,
                              void* d_out, int out_size, void* d_ws, size_t ws_size,
                              hipStream_t stream) {
    const float* x     = (const float*)d_in[0];
    const float* A     = (const float*)d_in[1];
    const float* ga    = (const float*)d_in[2];
    // d_in[3..6] = a_w, a_b, b_w, b_b: provably unused (softmax over contracted axis sums to 1)
    const float* gw    = (const float*)d_in[7];
    const float* gb    = (const float*)d_in[8];
    const float* gamma = (const float*)d_in[9];
    const float* beta  = (const float*)d_in[10];
    float* ws  = (float*)d_ws;
    float* out = (float*)d_out;

    hipLaunchKernelGGL(k_weff,  dim3(400), dim3(256), 0, stream, A, ga, gw, gb, ws);
    hipLaunchKernelGGL(k_stats, dim3(NN*NCHUNK), dim3(256), 0, stream,
                       x, ws + WS_W, ws + WS_GSUM, ws + WS_GSQ);
    hipLaunchKernelGGL(k_mid,   dim3(400), dim3(256), 0, stream, ws, gamma, beta);
    hipLaunchKernelGGL(k_final, dim3(NN*NCHUNK), dim3(256), 0, stream, x, ws, out);
}

// Round 5
// 646.967 us; speedup vs baseline: 2.0397x; 1.2369x over previous
//
#include <hip/hip_runtime.h>

// Problem constants
#define NN 128
#define CC 64          // C_IN == C_OUT
#define TT 256
#define VV 25
#define NSUB 3
#define TCH 8                  // t-rows per block tile
#define LPOS (TCH*VV)          // 200 positions per block tile
#define NCHUNK (TT/TCH)        // 32 chunks per n
#define CNT (NN*TT*VV)         // 819200 positions per channel
#define XSTR 204               // padded LDS row stride (%4==0 so float4 staging stays aligned)
#define WROW (VV*CC)           // 1600: c-row stride of transposed W [c][v][o]

// workspace layout (float offsets)
#define WS_BEFF 80      // 64:  b_eff
#define WS_GSUM 144     // 64:  global sum of y (hidden minus bias)
#define WS_GSQ  208     // 64:  global sum of y^2
#define WS_W    320     // 25*64*64: W stored TRANSPOSED [c][v][o]; then in-place M_fin
#define WS_BFIN (WS_W + VV*CC*CC)   // 64: folded bias

// fused: rowsums (in LDS), W_eff build (transposed), b_eff, and gsum/gsq zeroing
__global__ void k_weff(const float* __restrict__ A, const float* __restrict__ ga,
                       const float* __restrict__ gw, const float* __restrict__ gb,
                       float* __restrict__ ws) {
    __shared__ float S[NSUB*VV];
    int tid = threadIdx.x;
    if (tid < NSUB*VV) {
        int i = tid / VV, v = tid % VV;
        const float* pa = A  + (i*VV + v)*VV;
        const float* pg = ga + (i*VV + v)*VV;
        float s = 0.f;
        for (int w2 = 0; w2 < VV; ++w2) s += pa[w2] + pg[w2];
        S[tid] = s;
    }
    __syncthreads();
    int idx = blockIdx.x*256 + tid;
    int v = idx >> 12;
    int c = (idx >> 6) & 63;
    int o = idx & 63;
    float acc = 0.f;
    #pragma unroll
    for (int i = 0; i < NSUB; ++i)
        acc = fmaf(gw[(i*CC + o)*CC + c], 1.f + S[i*VV + v], acc);
    ws[WS_W + c*WROW + v*CC + o] = acc;          // transposed store [c][v][o]
    if (blockIdx.x == 0 && tid < CC)
        ws[WS_BEFF + tid] = gb[tid] + gb[CC + tid] + gb[2*CC + tid];
    if (blockIdx.x == 1 && tid < 128)
        ws[WS_GSUM + tid] = 0.f;   // zeros gsum(64)+gsq(64), contiguous
}

// Heavy pass structure (k_stats / k_final):
//   block = (n, 8-t chunk); Xs[c][t*25+v] staged coalesced, row stride 204.
//   thread (tid<200): og = tid&7 (o-octet), v = tid>>3. Holds xv[8] (t) and
//   acc[8][8] -> 2 W float4 loads per c serve 64 FMAs (32 FMA/load).
//   W is [c][v][o]: a wave (8 v x 8 og) reads a CONTIGUOUS 1024B chunk of one
//   256B-aligned c-row per load instr -- no gather.
//   RULE: every index into acc[][] must be a compile-time constant (r3/r4
//   spills both came from runtime-indexed acc -> scratch, +400-600MB WRITE).
__global__ __launch_bounds__(256, 3) void k_stats(const float* __restrict__ x,
                                                  const float* __restrict__ wsw,
                                                  float* __restrict__ gsum,
                                                  float* __restrict__ gsq) {
    __shared__ __align__(16) float Xs[CC*XSTR];
    __shared__ float s_sum[CC], s_sq[CC];
    int tid = threadIdx.x;
    int n = blockIdx.x >> 5, ch = blockIdx.x & 31;
    const float* xb = x + (size_t)n*(CC*TT*VV) + ch*LPOS;
    if (tid < CC) { s_sum[tid] = 0.f; s_sq[tid] = 0.f; }
    for (int i4 = tid; i4 < CC*(LPOS/4); i4 += 256) {
        int c = i4 / (LPOS/4), j4 = i4 - c*(LPOS/4);
        *(float4*)&Xs[c*XSTR + j4*4] = *(const float4*)(xb + c*(TT*VV) + j4*4);
    }
    __syncthreads();
    if (tid < 200) {
        int og = tid & 7, v = tid >> 3, o0 = og*8;
        float acc[TCH][8];
        #pragma unroll
        for (int t = 0; t < TCH; ++t)
            #pragma unroll
            for (int b = 0; b < 8; ++b) acc[t][b] = 0.f;
        const float* wp = wsw + v*CC + o0;       // [c][v][o], c-stride WROW
        const float* xp = Xs + v;
        #pragma unroll 4
        for (int c = 0; c < CC; ++c) {
            const float* wr = wp + c*WROW;
            float4 w0 = *(const float4*)(wr);
            float4 w1 = *(const float4*)(wr + 4);
            float xv[TCH];
            #pragma unroll
            for (int t = 0; t < TCH; ++t) xv[t] = xp[c*XSTR + t*VV];
            #pragma unroll
            for (int t = 0; t < TCH; ++t) {
                float xx = xv[t];
                acc[t][0] = fmaf(xx, w0.x, acc[t][0]);
                acc[t][1] = fmaf(xx, w0.y, acc[t][1]);
                acc[t][2] = fmaf(xx, w0.z, acc[t][2]);
                acc[t][3] = fmaf(xx, w0.w, acc[t][3]);
                acc[t][4] = fmaf(xx, w1.x, acc[t][4]);
                acc[t][5] = fmaf(xx, w1.y, acc[t][5]);
                acc[t][6] = fmaf(xx, w1.z, acc[t][6]);
                acc[t][7] = fmaf(xx, w1.w, acc[t][7]);
            }
        }
        #pragma unroll
        for (int oi = 0; oi < 8; ++oi) {
            float s1 = 0.f, s2 = 0.f;
            #pragma unroll
            for (int t = 0; t < TCH; ++t) {
                s1 += acc[t][oi];
                s2 = fmaf(acc[t][oi], acc[t][oi], s2);
            }
            atomicAdd(&s_sum[o0+oi], s1);
            atomicAdd(&s_sq[o0+oi],  s2);
        }
    }
    __syncthreads();
    if (tid < CC) {
        atomicAdd(&gsum[tid], s_sum[tid]);
        atomicAdd(&gsq[tid],  s_sq[tid]);
    }
}

// fold BN into the matrix in-place: M = alpha*W + I; b_fin = beta + alpha*(b_eff - mean)
// idx decodes the TRANSPOSED layout [c][v][o]: o = idx&63 (WROW%64==0), c = idx/WROW
__global__ void k_mid(float* __restrict__ ws, const float* __restrict__ gamma,
                      const float* __restrict__ beta) {
    int idx = blockIdx.x*256 + threadIdx.x;
    int o = idx & 63;
    int c = idx / WROW;
    float b     = ws[WS_BEFF + o];
    float meanY = ws[WS_GSUM + o] * (1.f/CNT);
    float ey2   = ws[WS_GSQ  + o] * (1.f/CNT);
    float m   = meanY + b;                          // E[hidden]
    float var = ey2 + 2.f*b*meanY + b*b - m*m;      // biased variance
    float alpha = gamma[o] * rsqrtf(var + 1e-5f);
    float wv = ws[WS_W + idx];
    ws[WS_W + idx] = fmaf(alpha, wv, (c == o) ? 1.f : 0.f);  // fold identity residual
    if (blockIdx.x == 0 && threadIdx.x < CC)
        ws[WS_BFIN + o] = fmaf(alpha, b - m, beta[o]);
}

__global__ __launch_bounds__(256, 3) void k_final(const float* __restrict__ x,
                                                  const float* __restrict__ ws,
                                                  float* __restrict__ out) {
    __shared__ __align__(16) float Xs[CC*XSTR];
    int tid = threadIdx.x;
    int n = blockIdx.x >> 5, ch = blockIdx.x & 31;
    const float* xb = x + (size_t)n*(CC*TT*VV) + ch*LPOS;
    for (int i4 = tid; i4 < CC*(LPOS/4); i4 += 256) {
        int c = i4 / (LPOS/4), j4 = i4 - c*(LPOS/4);
        *(float4*)&Xs[c*XSTR + j4*4] = *(const float4*)(xb + c*(TT*VV) + j4*4);
    }
    __syncthreads();
    if (tid < 200) {
        int og = tid & 7, v = tid >> 3, o0 = og*8;
        float acc[TCH][8];
        #pragma unroll
        for (int t = 0; t < TCH; ++t)
            #pragma unroll
            for (int b = 0; b < 8; ++b) acc[t][b] = 0.f;
        const float* wp = ws + WS_W + v*CC + o0;
        const float* xp = Xs + v;
        #pragma unroll 4
        for (int c = 0; c < CC; ++c) {
            const float* wr = wp + c*WROW;
            float4 w0 = *(const float4*)(wr);
            float4 w1 = *(const float4*)(wr + 4);
            float xv[TCH];
            #pragma unroll
            for (int t = 0; t < TCH; ++t) xv[t] = xp[c*XSTR + t*VV];
            #pragma unroll
            for (int t = 0; t < TCH; ++t) {
                float xx = xv[t];
                acc[t][0] = fmaf(xx, w0.x, acc[t][0]);
                acc[t][1] = fmaf(xx, w0.y, acc[t][1]);
                acc[t][2] = fmaf(xx, w0.z, acc[t][2]);
                acc[t][3] = fmaf(xx, w0.w, acc[t][3]);
                acc[t][4] = fmaf(xx, w1.x, acc[t][4]);
                acc[t][5] = fmaf(xx, w1.y, acc[t][5]);
                acc[t][6] = fmaf(xx, w1.z, acc[t][6]);
                acc[t][7] = fmaf(xx, w1.w, acc[t][7]);
            }
        }
        // y writeback into the (dead) column-v address set of Xs.
        // Each thread reads/writes ONLY its own column v -> race-free.
        // STATIC indices only (oi, t are literals after unroll); the resulting
        // 8-way LDS bank conflict (~1.1K cyc/wave) is accepted -- it is 100x
        // cheaper than the 210MB scratch spill the runtime-rotated version cost.
        #pragma unroll
        for (int oi = 0; oi < 8; ++oi) {
            float bfo = ws[WS_BFIN + o0 + oi];
            #pragma unroll
            for (int t = 0; t < TCH; ++t)
                Xs[(o0+oi)*XSTR + t*VV + v] = fmaxf(acc[t][oi] + bfo, 0.f);
        }
    }
    __syncthreads();
    // coalesced float4 readout: Xs rows hold y[o][t*25+v]
    float* ob = out + (size_t)n*(CC*TT*VV) + ch*LPOS;
    for (int i4 = tid; i4 < CC*(LPOS/4); i4 += 256) {
        int o = i4 / (LPOS/4), j4 = i4 - o*(LPOS/4);
        *(float4*)(ob + o*(TT*VV) + j4*4) = *(const float4*)&Xs[o*XSTR + j4*4];
    }
}

extern "C" void kernel_launch(void* const* d_in, const int* in_sizes, int n_in,
                              void* d_out, int out_size, void* d_ws, size_t ws_size,
                              hipStream_t stream) {
    const float* x     = (const float*)d_in[0];
    const float* A     = (const float*)d_in[1];
    const float* ga    = (const float*)d_in[2];
    // d_in[3..6] = a_w, a_b, b_w, b_b: provably unused (softmax over contracted axis sums to 1)
    const float* gw    = (const float*)d_in[7];
    const float* gb    = (const float*)d_in[8];
    const float* gamma = (const float*)d_in[9];
    const float* beta  = (const float*)d_in[10];
    float* ws  = (float*)d_ws;
    float* out = (float*)d_out;

    hipLaunchKernelGGL(k_weff,  dim3(400), dim3(256), 0, stream, A, ga, gw, gb, ws);
    hipLaunchKernelGGL(k_stats, dim3(NN*NCHUNK), dim3(256), 0, stream,
                       x, ws + WS_W, ws + WS_GSUM, ws + WS_GSQ);
    hipLaunchKernelGGL(k_mid,   dim3(400), dim3(256), 0, stream, ws, gamma, beta);
    hipLaunchKernelGGL(k_final, dim3(NN*NCHUNK), dim3(256), 0, stream, x, ws, out);
}